// Round 1
// baseline (444.229 us; speedup 1.0000x reference)
//
#include <hip/hip_runtime.h>
#include <hip/hip_bf16.h>

typedef short s16x8 __attribute__((ext_vector_type(8)));
typedef unsigned short u16x4 __attribute__((ext_vector_type(4)));
typedef float f32x4 __attribute__((ext_vector_type(4)));

#define MFMA16(a,b,c) __builtin_amdgcn_mfma_f32_16x16x32_bf16((a),(b),(c),0,0,0)

__device__ __forceinline__ unsigned short f2bf(float x){
  unsigned int u = __float_as_uint(x);
  u += 0x7fffu + ((u >> 16) & 1u);
  return (unsigned short)(u >> 16);
}

__device__ __forceinline__ void gl_lds16(const unsigned short* g, unsigned short* l){
  __builtin_amdgcn_global_load_lds((const __attribute__((address_space(1))) unsigned int*)g,
                                   (__attribute__((address_space(3))) unsigned int*)l, 16, 0, 0);
}

// ---------------- weight prep: W[k][n] fp32 -> Wt[n][k] bf16 ----------------
__global__ void __launch_bounds__(256) wt_prep(const float* __restrict__ Wq, const float* __restrict__ Wp,
                                               unsigned short* __restrict__ WqT, unsigned short* __restrict__ WpT){
  const int idx = blockIdx.x*256 + threadIdx.x;
  if (idx < 786432){                       // 1536*512
    const int nn = idx >> 9, kk = idx & 511;
    WqT[idx] = f2bf(Wq[kk*1536 + nn]);
  } else {
    const int i2 = idx - 786432;           // 512*512
    const int nn = i2 >> 9, kk = i2 & 511;
    WpT[i2] = f2bf(Wp[kk*512 + nn]);
  }
}

// ---------------- x (b,c,f,t) fp32 -> h [n=b*64+f][t][c] bf16 ----------------
__global__ void __launch_bounds__(256) x_to_h(const float* __restrict__ x, unsigned short* __restrict__ h){
  __shared__ unsigned short tb[64][65];
  const int blk = blockIdx.x;
  const int ttt = blk & 7, cht = (blk >> 3) & 7, n = blk >> 6;
  const int b = n >> 6, f = n & 63;
  const int t = threadIdx.x;
  const int tt0 = ttt*64, ch0 = cht*64;
  const float* xb = x + ((size_t)(b*512 + ch0)*64 + f)*512 + tt0;
  const int ttl = t & 63;
  #pragma unroll
  for (int it = 0; it < 16; ++it){
    const int chl = it*4 + (t >> 6);
    tb[chl][ttl] = f2bf(xb[(size_t)chl*32768 + ttl]);
  }
  __syncthreads();
  unsigned short* hb = h + ((size_t)n*512 + tt0)*512 + ch0;
  const int c2 = (t & 31)*2;
  #pragma unroll
  for (int it = 0; it < 8; ++it){
    const int ttw = it*8 + (t >> 5);
    unsigned int v = (unsigned int)tb[c2][ttw] | ((unsigned int)tb[c2+1][ttw] << 16);
    *(unsigned int*)(hb + (size_t)ttw*512 + c2) = v;
  }
}

// ---------------- shared 128x128 GEMM core, K=512, BK=64, bf16 ----------------
// A [M][512] row-major bf16, Bt [N][512] row-major bf16 (i.e. B^T).
// LDS XOR swizzle: 16B granule g stored at position g ^ (row&7); achieved by
// pre-swizzling the per-lane GLOBAL source (global_load_lds dest is linear).
__device__ __forceinline__ void gemm_core_128(const unsigned short* __restrict__ A,
                                              const unsigned short* __restrict__ Bt,
                                              char* smem, int bm, int bn, int tid,
                                              f32x4 (&acc)[4][4]){
  const int lane = tid & 63, w = tid >> 6;
  const int wr = w >> 1, wc = w & 1;
  const int glog = (lane & 7) ^ ((lane >> 3) & 7);
  const unsigned short* Ab = A  + (size_t)(bm*128 + w*32 + (lane>>3))*512 + glog*8;
  const unsigned short* Bb = Bt + (size_t)(bn*128 + w*32 + (lane>>3))*512 + glog*8;
  unsigned short* AsW = (unsigned short*)smem + w*2048;
  unsigned short* BsW = (unsigned short*)(smem + 16384) + w*2048;
  const int rowoff = (lane & 15)*128;      // row byte offset within quadrant
  const int axor = lane & 7;
  const int ag = lane >> 4;
  for (int kt = 0; kt < 8; ++kt){
    const unsigned short* Ag = Ab + kt*64;
    const unsigned short* Bg = Bb + kt*64;
    gl_lds16(Ag          , AsW);
    gl_lds16(Ag +  8*512 , AsW + 512);
    gl_lds16(Ag + 16*512 , AsW + 1024);
    gl_lds16(Ag + 24*512 , AsW + 1536);
    gl_lds16(Bg          , BsW);
    gl_lds16(Bg +  8*512 , BsW + 512);
    gl_lds16(Bg + 16*512 , BsW + 1024);
    gl_lds16(Bg + 24*512 , BsW + 1536);
    __syncthreads();
    #pragma unroll
    for (int ks = 0; ks < 2; ++ks){
      s16x8 av[4], bv[4];
      const int g16 = ((ks*4 + ag) ^ axor) * 16;
      #pragma unroll
      for (int i = 0; i < 4; ++i){
        av[i] = *(const s16x8*)(smem +         (wr*64 + i*16)*128 + rowoff + g16);
        bv[i] = *(const s16x8*)(smem + 16384 + (wc*64 + i*16)*128 + rowoff + g16);
      }
      #pragma unroll
      for (int i = 0; i < 4; ++i)
        #pragma unroll
        for (int j = 0; j < 4; ++j)
          acc[i][j] = MFMA16(av[i], bv[j], acc[i][j]);
    }
    __syncthreads();
  }
}

// ---------------- QKV GEMM: h @ WqkvT -> Q,K [nh][t][64], V^T [nh][64][t] ----------------
__global__ void __launch_bounds__(256) qkv_gemm(const unsigned short* __restrict__ h,
                                                const unsigned short* __restrict__ WqT,
                                                const float* __restrict__ bqkv,
                                                unsigned short* __restrict__ Qb,
                                                unsigned short* __restrict__ Kb,
                                                unsigned short* __restrict__ Vt){
  __shared__ __align__(16) char smem[34816];
  const int tid = threadIdx.x;
  const int bm = blockIdx.x / 12, bn = blockIdx.x % 12;
  f32x4 acc[4][4] = {};
  gemm_core_128(h, WqT, smem, bm, bn, tid, acc);
  const int lane = tid & 63, w = tid >> 6, wr = w >> 1, wc = w & 1;
  const int c0 = bn * 128;
  float bj[4];
  #pragma unroll
  for (int j = 0; j < 4; ++j) bj[j] = bqkv[c0 + wc*64 + j*16 + (lane & 15)];
  unsigned short* Cs = (unsigned short*)smem;   // [128][136] bf16 (reuses staging LDS)
  #pragma unroll
  for (int i = 0; i < 4; ++i)
    #pragma unroll
    for (int j = 0; j < 4; ++j)
      #pragma unroll
      for (int r = 0; r < 4; ++r){
        const int row = wr*64 + i*16 + (lane>>4)*4 + r;
        const int col = wc*64 + j*16 + (lane & 15);
        Cs[row*136 + col] = f2bf(acc[i][j][r] + bj[j]);
      }
  __syncthreads();
  const int n = bm >> 2, tt0 = (bm & 3) * 128;
  const int sel = bn >> 2, cq0 = (bn & 3) * 128;
  if (sel < 2){
    unsigned short* dst = (sel == 0) ? Qb : Kb;
    #pragma unroll
    for (int it = 0; it < 8; ++it){
      const int idx = it*256 + tid;
      const int row = idx >> 4, colc = (idx & 15)*8;
      const int cq = cq0 + colc, head = cq >> 6, d0 = cq & 63;
      s16x8 v = *(const s16x8*)(Cs + row*136 + colc);
      *(s16x8*)(dst + ((size_t)(n*8 + head)*512 + tt0 + row)*64 + d0) = v;
    }
  } else {
    const int col = tid >> 1;
    const int cq = cq0 + col, head = cq >> 6, d = cq & 63;
    #pragma unroll
    for (int it = 0; it < 8; ++it){
      const int ttl0 = (it*2 + (tid & 1))*8;
      s16x8 v;
      #pragma unroll
      for (int r = 0; r < 8; ++r) v[r] = (short)Cs[(ttl0 + r)*136 + col];
      *(s16x8*)(Vt + ((size_t)(n*8 + head)*64 + d)*512 + tt0 + ttl0) = v;
    }
  }
}

// ---------------- windowed attention, swapped-QK^T MFMA, online softmax ----------------
__global__ void __launch_bounds__(256) attn_kernel(const unsigned short* __restrict__ Qb,
                                                   const unsigned short* __restrict__ Kb,
                                                   const unsigned short* __restrict__ Vt,
                                                   const float* __restrict__ relb,
                                                   unsigned short* __restrict__ ys){
  __shared__ float biasS[128];
  __shared__ __align__(16) unsigned short P[4][16*72];   // per-wave P tile [16 q][64 kk], pad to 72
  const int blk = blockIdx.x;
  const int qb = blk & 7, hh = (blk >> 3) & 7, n = blk >> 6;
  const int tid = threadIdx.x, lane = tid & 63, w = tid >> 6;
  if (tid < 128) biasS[tid] = relb[hh*128 + tid];
  __syncthreads();
  const int q0 = qb*64, qw0 = q0 + w*16;
  const size_t nh = (size_t)(n*8 + hh);
  const int lq = lane & 15, lg = lane >> 4;
  const unsigned short* Qp = Qb + (nh*512 + qw0 + lq)*64 + lg*8;
  s16x8 bq0 = *(const s16x8*)(Qp);
  s16x8 bq1 = *(const s16x8*)(Qp + 32);
  f32x4 yacc[4] = {};
  float m_run = -INFINITY, l_run = 0.f;
  const int qg = qw0 + lq;
  unsigned short* Pw = P[w];
  for (int kt = 0; kt < 3; ++kt){
    const int kt0 = q0 - 128 + kt*64;
    if (kt0 < 0) continue;
    f32x4 s[4] = {};
    const unsigned short* Kp = Kb + (nh*512 + kt0 + lq)*64 + lg*8;
    #pragma unroll
    for (int mk = 0; mk < 4; ++mk){
      s16x8 kv0 = *(const s16x8*)(Kp + mk*1024);
      s16x8 kv1 = *(const s16x8*)(Kp + mk*1024 + 32);
      s[mk] = MFMA16(kv0, bq0, s[mk]);      // S^T[kk][q]
      s[mk] = MFMA16(kv1, bq1, s[mk]);
    }
    float pmax = -3.0e38f;
    float sv[4][4];
    #pragma unroll
    for (int mk = 0; mk < 4; ++mk)
      #pragma unroll
      for (int r = 0; r < 4; ++r){
        const int kkl = mk*16 + lg*4 + r;
        const int dist = qg - (kt0 + kkl);
        float xv;
        if (dist >= 0 && dist < 128) xv = s[mk][r]*0.125f + biasS[dist];
        else                         xv = -1.0e30f;
        sv[mk][r] = xv;
        pmax = fmaxf(pmax, xv);
      }
    pmax = fmaxf(pmax, __shfl_xor(pmax, 16, 64));
    pmax = fmaxf(pmax, __shfl_xor(pmax, 32, 64));
    const float m_new = fmaxf(m_run, pmax);
    const float scalef = __expf(m_run - m_new);
    float psum = 0.f;
    #pragma unroll
    for (int mk = 0; mk < 4; ++mk){
      u16x4 pk;
      #pragma unroll
      for (int r = 0; r < 4; ++r){
        const float pe = __expf(sv[mk][r] - m_new);
        psum += pe;
        pk[r] = f2bf(pe);
      }
      *(u16x4*)(Pw + lq*72 + mk*16 + lg*4) = pk;
    }
    psum += __shfl_xor(psum, 16, 64);
    psum += __shfl_xor(psum, 32, 64);
    l_run = l_run*scalef + psum;
    m_run = m_new;
    #pragma unroll
    for (int i = 0; i < 4; ++i) yacc[i] *= scalef;
    const unsigned short* Vp = Vt + (nh*64 + lq)*512 + kt0 + lg*8;
    #pragma unroll
    for (int ks2 = 0; ks2 < 2; ++ks2){
      s16x8 pb = *(const s16x8*)(Pw + lq*72 + ks2*32 + lg*8);
      #pragma unroll
      for (int i = 0; i < 4; ++i){
        s16x8 vv = *(const s16x8*)(Vp + i*8192 + ks2*32);
        yacc[i] = MFMA16(vv, pb, yacc[i]);  // y^T[d][q]
      }
    }
  }
  const float inv = 1.f / l_run;
  unsigned short* yp = ys + ((size_t)n*512 + qw0 + lq)*512 + hh*64 + lg*4;
  #pragma unroll
  for (int i = 0; i < 4; ++i){
    u16x4 o;
    #pragma unroll
    for (int r = 0; r < 4; ++r) o[r] = f2bf(yacc[i][r]*inv);
    *(u16x4*)(yp + i*16) = o;
  }
}

// ---------------- proj GEMM: ys @ WprojT + b -> out (b,c,f,t) fp32 ----------------
__global__ void __launch_bounds__(256) proj_gemm(const unsigned short* __restrict__ ys,
                                                 const unsigned short* __restrict__ WpT,
                                                 const float* __restrict__ bproj,
                                                 float* __restrict__ out){
  __shared__ __align__(16) char smem[34816];
  const int tid = threadIdx.x;
  const int bm = blockIdx.x >> 2, bn = blockIdx.x & 3;
  f32x4 acc[4][4] = {};
  gemm_core_128(ys, WpT, smem, bm, bn, tid, acc);
  const int lane = tid & 63, w = tid >> 6, wr = w >> 1, wc = w & 1;
  const int c0 = bn * 128;
  float bj[4];
  #pragma unroll
  for (int j = 0; j < 4; ++j) bj[j] = bproj[c0 + wc*64 + j*16 + (lane & 15)];
  float* Cs = (float*)smem;                 // [64][133] fp32, two half-tiles
  const int n = bm >> 2, b = n >> 6, f = n & 63, tt0 = (bm & 3)*128;
  #pragma unroll
  for (int p = 0; p < 2; ++p){
    __syncthreads();
    if (wr == p){
      #pragma unroll
      for (int i = 0; i < 4; ++i)
        #pragma unroll
        for (int j = 0; j < 4; ++j)
          #pragma unroll
          for (int r = 0; r < 4; ++r){
            const int rowl = i*16 + (lane>>4)*4 + r;
            const int col = wc*64 + j*16 + (lane & 15);
            Cs[rowl*133 + col] = acc[i][j][r] + bj[j];
          }
    }
    __syncthreads();
    #pragma unroll
    for (int it = 0; it < 8; ++it){
      const int idx = it*256 + tid;
      const int chl = idx >> 4, tc = (idx & 15)*4;
      f32x4 v;
      #pragma unroll
      for (int r = 0; r < 4; ++r) v[r] = Cs[(tc + r)*133 + chl];
      const int ch = c0 + chl;
      *(f32x4*)(out + ((size_t)(b*512 + ch)*64 + f)*512 + tt0 + p*64 + tc) = v;
    }
  }
}

extern "C" void kernel_launch(void* const* d_in, const int* in_sizes, int n_in,
                              void* d_out, int out_size, void* d_ws, size_t ws_size,
                              hipStream_t stream){
  const float* x     = (const float*)d_in[0];
  const float* Wqkv  = (const float*)d_in[1];
  const float* bqkv  = (const float*)d_in[2];
  const float* Wproj = (const float*)d_in[3];
  const float* bproj = (const float*)d_in[4];
  const float* relb  = (const float*)d_in[5];
  float* out = (float*)d_out;
  char* ws = (char*)d_ws;
  if (ws_size < (size_t)270532608) return;   // need ~258 MiB scratch
  unsigned short* hbuf = (unsigned short*)(ws);                      // 64 MiB; reused as ys after QKV
  unsigned short* Qb   = (unsigned short*)(ws + (size_t)67108864);   // 64 MiB
  unsigned short* Kb   = (unsigned short*)(ws + (size_t)134217728);  // 64 MiB
  unsigned short* Vt   = (unsigned short*)(ws + (size_t)201326592);  // 64 MiB
  unsigned short* WqT  = (unsigned short*)(ws + (size_t)268435456);  // 1.5 MiB
  unsigned short* WpT  = (unsigned short*)(ws + (size_t)270008320);  // 0.5 MiB

  hipLaunchKernelGGL(wt_prep,     dim3(4096), dim3(256), 0, stream, Wqkv, Wproj, WqT, WpT);
  hipLaunchKernelGGL(x_to_h,      dim3(8192), dim3(256), 0, stream, x, hbuf);
  hipLaunchKernelGGL(qkv_gemm,    dim3(6144), dim3(256), 0, stream, hbuf, WqT, bqkv, Qb, Kb, Vt);
  hipLaunchKernelGGL(attn_kernel, dim3(8192), dim3(256), 0, stream, Qb, Kb, Vt, relb, hbuf);
  hipLaunchKernelGGL(proj_gemm,   dim3(2048), dim3(256), 0, stream, hbuf, WpT, bproj, out);
}

// Round 2
// 386.540 us; speedup vs baseline: 1.1492x; 1.1492x over previous
//
#include <hip/hip_runtime.h>
#include <hip/hip_bf16.h>

typedef short s16x8 __attribute__((ext_vector_type(8)));
typedef unsigned short u16x4 __attribute__((ext_vector_type(4)));
typedef float f32x4 __attribute__((ext_vector_type(4)));

#define MFMA16(a,b,c) __builtin_amdgcn_mfma_f32_16x16x32_bf16((a),(b),(c),0,0,0)

__device__ __forceinline__ unsigned short f2bf(float x){
  unsigned int u = __float_as_uint(x);
  u += 0x7fffu + ((u >> 16) & 1u);
  return (unsigned short)(u >> 16);
}

__device__ __forceinline__ void gl_lds16(const unsigned short* g, unsigned short* l){
  __builtin_amdgcn_global_load_lds((const __attribute__((address_space(1))) unsigned int*)g,
                                   (__attribute__((address_space(3))) unsigned int*)l, 16, 0, 0);
}

// ---------------- weight prep: W[k][n] fp32 -> Wt[n][k] bf16 (LDS transpose) ----------------
__global__ void __launch_bounds__(256) wt_prep(const float* __restrict__ Wq, const float* __restrict__ Wp,
                                               unsigned short* __restrict__ WqT, unsigned short* __restrict__ WpT){
  __shared__ unsigned short tb[64][65];
  int blk = blockIdx.x;
  const float* src; unsigned short* dst; int N, k0, n0;
  if (blk < 192){                       // Wqkv: 24 n-tiles x 8 k-tiles
    src = Wq; dst = WqT; N = 1536;
    n0 = (blk % 24)*64; k0 = (blk / 24)*64;
  } else {                              // Wproj: 8 x 8
    blk -= 192; src = Wp; dst = WpT; N = 512;
    n0 = (blk & 7)*64; k0 = (blk >> 3)*64;
  }
  const int tid = threadIdx.x;
  const int nl = tid & 63;
  #pragma unroll
  for (int it = 0; it < 16; ++it){
    const int kl = it*4 + (tid >> 6);
    tb[kl][nl] = f2bf(src[(size_t)(k0+kl)*N + n0 + nl]);
  }
  __syncthreads();
  const int c2 = (tid & 31)*2;
  #pragma unroll
  for (int it = 0; it < 8; ++it){
    const int nw = it*8 + (tid >> 5);
    unsigned int v = (unsigned int)tb[c2][nw] | ((unsigned int)tb[c2+1][nw] << 16);
    *(unsigned int*)(dst + (size_t)(n0+nw)*512 + k0 + c2) = v;
  }
}

// ---------------- x (b,c,f,t) fp32 -> h [n=b*64+f][t][c] bf16 ----------------
__global__ void __launch_bounds__(256) x_to_h(const float* __restrict__ x, unsigned short* __restrict__ h){
  __shared__ unsigned short tb[64][65];
  const int blk = blockIdx.x;
  const int ttt = blk & 7, cht = (blk >> 3) & 7, n = blk >> 6;
  const int b = n >> 6, f = n & 63;
  const int t = threadIdx.x;
  const int tt0 = ttt*64, ch0 = cht*64;
  const float* xb = x + ((size_t)(b*512 + ch0)*64 + f)*512 + tt0;
  const int ttl = t & 63;
  #pragma unroll
  for (int it = 0; it < 16; ++it){
    const int chl = it*4 + (t >> 6);
    tb[chl][ttl] = f2bf(xb[(size_t)chl*32768 + ttl]);
  }
  __syncthreads();
  unsigned short* hb = h + ((size_t)n*512 + tt0)*512 + ch0;
  const int c2 = (t & 31)*2;
  #pragma unroll
  for (int it = 0; it < 8; ++it){
    const int ttw = it*8 + (t >> 5);
    unsigned int v = (unsigned int)tb[c2][ttw] | ((unsigned int)tb[c2+1][ttw] << 16);
    *(unsigned int*)(hb + (size_t)ttw*512 + c2) = v;
  }
}

// ---------------- shared 128x128 GEMM core, K=512, BK=64, bf16 ----------------
__device__ __forceinline__ void gemm_core_128(const unsigned short* __restrict__ A,
                                              const unsigned short* __restrict__ Bt,
                                              char* smem, int bm, int bn, int tid,
                                              f32x4 (&acc)[4][4]){
  const int lane = tid & 63, w = tid >> 6;
  const int wr = w >> 1, wc = w & 1;
  const int glog = (lane & 7) ^ ((lane >> 3) & 7);
  const unsigned short* Ab = A  + (size_t)(bm*128 + w*32 + (lane>>3))*512 + glog*8;
  const unsigned short* Bb = Bt + (size_t)(bn*128 + w*32 + (lane>>3))*512 + glog*8;
  unsigned short* AsW = (unsigned short*)smem + w*2048;
  unsigned short* BsW = (unsigned short*)(smem + 16384) + w*2048;
  const int rowoff = (lane & 15)*128;
  const int axor = lane & 7;
  const int ag = lane >> 4;
  for (int kt = 0; kt < 8; ++kt){
    const unsigned short* Ag = Ab + kt*64;
    const unsigned short* Bg = Bb + kt*64;
    gl_lds16(Ag          , AsW);
    gl_lds16(Ag +  8*512 , AsW + 512);
    gl_lds16(Ag + 16*512 , AsW + 1024);
    gl_lds16(Ag + 24*512 , AsW + 1536);
    gl_lds16(Bg          , BsW);
    gl_lds16(Bg +  8*512 , BsW + 512);
    gl_lds16(Bg + 16*512 , BsW + 1024);
    gl_lds16(Bg + 24*512 , BsW + 1536);
    __syncthreads();
    #pragma unroll
    for (int ks = 0; ks < 2; ++ks){
      s16x8 av[4], bv[4];
      const int g16 = ((ks*4 + ag) ^ axor) * 16;
      #pragma unroll
      for (int i = 0; i < 4; ++i){
        av[i] = *(const s16x8*)(smem +         (wr*64 + i*16)*128 + rowoff + g16);
        bv[i] = *(const s16x8*)(smem + 16384 + (wc*64 + i*16)*128 + rowoff + g16);
      }
      #pragma unroll
      for (int i = 0; i < 4; ++i)
        #pragma unroll
        for (int j = 0; j < 4; ++j)
          acc[i][j] = MFMA16(av[i], bv[j], acc[i][j]);
    }
    __syncthreads();
  }
}

// ---------------- QKV GEMM: h @ WqkvT -> Q,K [nh][t][64], V^T [nh][64][t] ----------------
__global__ void __launch_bounds__(256) qkv_gemm(const unsigned short* __restrict__ h,
                                                const unsigned short* __restrict__ WqT,
                                                const float* __restrict__ bqkv,
                                                unsigned short* __restrict__ Qb,
                                                unsigned short* __restrict__ Kb,
                                                unsigned short* __restrict__ Vt){
  __shared__ __align__(16) char smem[34816];
  const int tid = threadIdx.x;
  const int bm = blockIdx.x / 12, bn = blockIdx.x % 12;
  f32x4 acc[4][4] = {};
  gemm_core_128(h, WqT, smem, bm, bn, tid, acc);
  const int lane = tid & 63, w = tid >> 6, wr = w >> 1, wc = w & 1;
  const int c0 = bn * 128;
  float bj[4];
  #pragma unroll
  for (int j = 0; j < 4; ++j) bj[j] = bqkv[c0 + wc*64 + j*16 + (lane & 15)];
  unsigned short* Cs = (unsigned short*)smem;   // [128][136] bf16
  #pragma unroll
  for (int i = 0; i < 4; ++i)
    #pragma unroll
    for (int j = 0; j < 4; ++j)
      #pragma unroll
      for (int r = 0; r < 4; ++r){
        const int row = wr*64 + i*16 + (lane>>4)*4 + r;
        const int col = wc*64 + j*16 + (lane & 15);
        Cs[row*136 + col] = f2bf(acc[i][j][r] + bj[j]);
      }
  __syncthreads();
  const int n = bm >> 2, tt0 = (bm & 3) * 128;
  const int sel = bn >> 2, cq0 = (bn & 3) * 128;
  if (sel < 2){
    unsigned short* dst = (sel == 0) ? Qb : Kb;
    #pragma unroll
    for (int it = 0; it < 8; ++it){
      const int idx = it*256 + tid;
      const int row = idx >> 4, colc = (idx & 15)*8;
      const int cq = cq0 + colc, head = cq >> 6, d0 = cq & 63;
      s16x8 v = *(const s16x8*)(Cs + row*136 + colc);
      *(s16x8*)(dst + ((size_t)(n*8 + head)*512 + tt0 + row)*64 + d0) = v;
    }
  } else {
    const int col = tid >> 1;
    const int cq = cq0 + col, head = cq >> 6, d = cq & 63;
    #pragma unroll
    for (int it = 0; it < 8; ++it){
      const int ttl0 = (it*2 + (tid & 1))*8;
      s16x8 v;
      #pragma unroll
      for (int r = 0; r < 8; ++r) v[r] = (short)Cs[(ttl0 + r)*136 + col];
      *(s16x8*)(Vt + ((size_t)(n*8 + head)*64 + d)*512 + tt0 + ttl0) = v;
    }
  }
}

// ---------------- windowed attention v2: LDS-staged K/V, double-buffered ----------------
// block = (n, h, 128-q tile); 4 waves x 32 q (2x16 qsub). k-window = 4 tiles of 64.
__global__ void __launch_bounds__(256) attn_kernel(const unsigned short* __restrict__ Qb,
                                                   const unsigned short* __restrict__ Kb,
                                                   const unsigned short* __restrict__ Vt,
                                                   const float* __restrict__ relb,
                                                   unsigned short* __restrict__ ys){
  __shared__ __align__(16) unsigned short KsL[2][4096];   // [64 rows][8 gran][8] XOR-swizzled
  __shared__ __align__(16) unsigned short VsL[2][4096];
  __shared__ __align__(16) unsigned short P[4][2][16*72];
  __shared__ float biasS[128];
  const int blk = blockIdx.x;
  const int qt = blk & 3, hh = (blk >> 2) & 7, n = blk >> 5;
  const int tid = threadIdx.x, lane = tid & 63, w = tid >> 6;
  if (tid < 128) biasS[tid] = relb[hh*128 + tid];
  const int q0 = qt * 128;
  const size_t nh = (size_t)(n*8 + hh);
  const unsigned short* Kbase = Kb + nh*32768;
  const unsigned short* Vbase = Vt + nh*32768;
  const int lq = lane & 15, lg = lane >> 4;
  const int qq0 = q0 + w*32;
  // Q fragments for the wave's two 16-q subtiles
  s16x8 bq[2][2];
  #pragma unroll
  for (int qs = 0; qs < 2; ++qs){
    const unsigned short* Qp = Qb + (nh*512 + qq0 + qs*16 + lq)*64 + lg*8;
    bq[qs][0] = *(const s16x8*)(Qp);
    bq[qs][1] = *(const s16x8*)(Qp + 32);
  }
  // stage lane mapping (2 gl_lds16 per thread per tensor)
  int r_[2], g_[2], dsl_[2];
  #pragma unroll
  for (int j = 0; j < 2; ++j){
    const int slot = j*256 + w*64 + lane;
    r_[j] = slot >> 3;
    g_[j] = (slot & 7) ^ (r_[j] & 7);
    dsl_[j] = (j*256 + w*64) * 8;            // wave-uniform LDS element base
  }
  f32x4 yacc[2][4] = {{{0.f,0.f,0.f,0.f}}};
  float m_run[2] = {-INFINITY, -INFINITY}, l_run[2] = {0.f, 0.f};
  const int first = (q0 >= 128) ? 0 : ((128 - q0 + 63) >> 6);
  int cur = 0;
  {
    const int kt0 = q0 - 128 + first*64;
    #pragma unroll
    for (int j = 0; j < 2; ++j){
      gl_lds16(Kbase + (size_t)(kt0 + r_[j])*64 + g_[j]*8, KsL[0] + dsl_[j]);
      gl_lds16(Vbase + (size_t)r_[j]*512 + kt0 + g_[j]*8,  VsL[0] + dsl_[j]);
    }
  }
  for (int kt = first; kt < 4; ++kt){
    const int kt0 = q0 - 128 + kt*64;
    __syncthreads();                          // staged buf[cur] complete (vmcnt0 drained)
    if (kt < 3){                              // issue next tile into buf[cur^1]
      const int nk0 = kt0 + 64;
      #pragma unroll
      for (int j = 0; j < 2; ++j){
        gl_lds16(Kbase + (size_t)(nk0 + r_[j])*64 + g_[j]*8, KsL[cur^1] + dsl_[j]);
        gl_lds16(Vbase + (size_t)r_[j]*512 + nk0 + g_[j]*8,  VsL[cur^1] + dsl_[j]);
      }
    }
    const bool wact = (kt0 <= qq0 + 31);      // tile relevant to this wave at all
    if (wact){
      // K fragments (shared by both qsub)
      s16x8 av[4][2];
      #pragma unroll
      for (int mk = 0; mk < 4; ++mk){
        const int rr = mk*16 + lq;
        const unsigned short* kp = KsL[cur] + rr*64;
        av[mk][0] = *(const s16x8*)(kp + ((lg     ) ^ (rr & 7))*8);
        av[mk][1] = *(const s16x8*)(kp + ((4 + lg ) ^ (rr & 7))*8);
      }
      float pex[2][4][4];
      #pragma unroll
      for (int qs = 0; qs < 2; ++qs){
        const int qqs = qq0 + qs*16;
        if (kt0 > qqs + 15 || kt0 + 63 < qqs - 127) continue;
        f32x4 s4[4] = {{0.f,0.f,0.f,0.f}};
        #pragma unroll
        for (int mk = 0; mk < 4; ++mk){
          s4[mk] = MFMA16(av[mk][0], bq[qs][0], s4[mk]);
          s4[mk] = MFMA16(av[mk][1], bq[qs][1], s4[mk]);
        }
        const int qg = qqs + lq;
        float pmax = -3.0e38f;
        #pragma unroll
        for (int mk = 0; mk < 4; ++mk)
          #pragma unroll
          for (int r = 0; r < 4; ++r){
            const int dist = qg - (kt0 + mk*16 + lg*4 + r);
            float xv;
            if (dist >= 0 && dist < 128) xv = s4[mk][r]*0.125f + biasS[dist];
            else                         xv = -1.0e30f;
            pex[qs][mk][r] = xv;
            pmax = fmaxf(pmax, xv);
          }
        pmax = fmaxf(pmax, __shfl_xor(pmax, 16, 64));
        pmax = fmaxf(pmax, __shfl_xor(pmax, 32, 64));
        const float m_new = fmaxf(m_run[qs], pmax);
        const float scalef = __expf(m_run[qs] - m_new);
        float psum = 0.f;
        unsigned short* Pw = P[w][qs];
        #pragma unroll
        for (int mk = 0; mk < 4; ++mk){
          u16x4 pk;
          #pragma unroll
          for (int r = 0; r < 4; ++r){
            const float pe = __expf(pex[qs][mk][r] - m_new);
            psum += pe;
            pk[r] = f2bf(pe);
          }
          *(u16x4*)(Pw + lq*72 + mk*16 + lg*4) = pk;
        }
        psum += __shfl_xor(psum, 16, 64);
        psum += __shfl_xor(psum, 32, 64);
        l_run[qs] = l_run[qs]*scalef + psum;
        m_run[qs] = m_new;
        #pragma unroll
        for (int i = 0; i < 4; ++i) yacc[qs][i] *= scalef;
      }
      // V fragments (shared by both qsub)
      s16x8 vv[4][2];
      #pragma unroll
      for (int i = 0; i < 4; ++i){
        const int rr = i*16 + lq;
        const unsigned short* vp = VsL[cur] + rr*64;
        vv[i][0] = *(const s16x8*)(vp + ((lg    ) ^ (rr & 7))*8);
        vv[i][1] = *(const s16x8*)(vp + ((4 + lg) ^ (rr & 7))*8);
      }
      #pragma unroll
      for (int qs = 0; qs < 2; ++qs){
        const int qqs = qq0 + qs*16;
        if (kt0 > qqs + 15 || kt0 + 63 < qqs - 127) continue;
        unsigned short* Pw = P[w][qs];
        #pragma unroll
        for (int ks2 = 0; ks2 < 2; ++ks2){
          s16x8 pb = *(const s16x8*)(Pw + lq*72 + ks2*32 + lg*8);
          #pragma unroll
          for (int i = 0; i < 4; ++i)
            yacc[qs][i] = MFMA16(vv[i][ks2], pb, yacc[qs][i]);   // y^T[d][q]
        }
      }
    }
    cur ^= 1;
  }
  #pragma unroll
  for (int qs = 0; qs < 2; ++qs){
    const float inv = 1.f / l_run[qs];
    unsigned short* yp = ys + ((size_t)n*512 + qq0 + qs*16 + lq)*512 + hh*64 + lg*4;
    #pragma unroll
    for (int i = 0; i < 4; ++i){
      u16x4 o;
      #pragma unroll
      for (int r = 0; r < 4; ++r) o[r] = f2bf(yacc[qs][i][r]*inv);
      *(u16x4*)(yp + i*16) = o;
    }
  }
}

// ---------------- proj GEMM: ys @ WprojT + b -> out (b,c,f,t) fp32 ----------------
__global__ void __launch_bounds__(256) proj_gemm(const unsigned short* __restrict__ ys,
                                                 const unsigned short* __restrict__ WpT,
                                                 const float* __restrict__ bproj,
                                                 float* __restrict__ out){
  __shared__ __align__(16) char smem[34816];
  const int tid = threadIdx.x;
  const int bm = blockIdx.x >> 2, bn = blockIdx.x & 3;
  f32x4 acc[4][4] = {};
  gemm_core_128(ys, WpT, smem, bm, bn, tid, acc);
  const int lane = tid & 63, w = tid >> 6, wr = w >> 1, wc = w & 1;
  const int c0 = bn * 128;
  float bj[4];
  #pragma unroll
  for (int j = 0; j < 4; ++j) bj[j] = bproj[c0 + wc*64 + j*16 + (lane & 15)];
  float* Cs = (float*)smem;                 // [64][133] fp32, two half-tiles
  const int n = bm >> 2, b = n >> 6, f = n & 63, tt0 = (bm & 3)*128;
  #pragma unroll
  for (int p = 0; p < 2; ++p){
    __syncthreads();
    if (wr == p){
      #pragma unroll
      for (int i = 0; i < 4; ++i)
        #pragma unroll
        for (int j = 0; j < 4; ++j)
          #pragma unroll
          for (int r = 0; r < 4; ++r){
            const int rowl = i*16 + (lane>>4)*4 + r;
            const int col = wc*64 + j*16 + (lane & 15);
            Cs[rowl*133 + col] = acc[i][j][r] + bj[j];
          }
    }
    __syncthreads();
    #pragma unroll
    for (int it = 0; it < 8; ++it){
      const int idx = it*256 + tid;
      const int chl = idx >> 4, tc = (idx & 15)*4;
      f32x4 v;
      #pragma unroll
      for (int r = 0; r < 4; ++r) v[r] = Cs[(tc + r)*133 + chl];
      const int ch = c0 + chl;
      *(f32x4*)(out + ((size_t)(b*512 + ch)*64 + f)*512 + tt0 + p*64 + tc) = v;
    }
  }
}

extern "C" void kernel_launch(void* const* d_in, const int* in_sizes, int n_in,
                              void* d_out, int out_size, void* d_ws, size_t ws_size,
                              hipStream_t stream){
  const float* x     = (const float*)d_in[0];
  const float* Wqkv  = (const float*)d_in[1];
  const float* bqkv  = (const float*)d_in[2];
  const float* Wproj = (const float*)d_in[3];
  const float* bproj = (const float*)d_in[4];
  const float* relb  = (const float*)d_in[5];
  float* out = (float*)d_out;
  char* ws = (char*)d_ws;
  if (ws_size < (size_t)270532608) return;
  unsigned short* hbuf = (unsigned short*)(ws);                      // 64 MiB; reused as ys
  unsigned short* Qb   = (unsigned short*)(ws + (size_t)67108864);
  unsigned short* Kb   = (unsigned short*)(ws + (size_t)134217728);
  unsigned short* Vt   = (unsigned short*)(ws + (size_t)201326592);
  unsigned short* WqT  = (unsigned short*)(ws + (size_t)268435456);
  unsigned short* WpT  = (unsigned short*)(ws + (size_t)270008320);

  hipLaunchKernelGGL(wt_prep,     dim3(256),  dim3(256), 0, stream, Wqkv, Wproj, WqT, WpT);
  hipLaunchKernelGGL(x_to_h,      dim3(8192), dim3(256), 0, stream, x, hbuf);
  hipLaunchKernelGGL(qkv_gemm,    dim3(6144), dim3(256), 0, stream, hbuf, WqT, bqkv, Qb, Kb, Vt);
  hipLaunchKernelGGL(attn_kernel, dim3(4096), dim3(256), 0, stream, Qb, Kb, Vt, relb, hbuf);
  hipLaunchKernelGGL(proj_gemm,   dim3(2048), dim3(256), 0, stream, hbuf, WpT, bproj, out);
}